// Round 10
// baseline (781.088 us; speedup 1.0000x reference)
//
#include <hip/hip_runtime.h>
#include <cstdint>
#include <cstddef>

#define HID 128
#define BSHIFT 7            // 128 nodes per bucket -> nbuck = 782 for N=100000
#define NSB 256             // scatter blocks (pass1/pass2 chunking)
#define MAXB 4096           // LDS sort capacity (avg bucket = 2046 edges)

// ------------- fused weight transposes (1 launch instead of 5) -------------
__global__ __launch_bounds__(256)
void transpose_all_kernel(const float* __restrict__ W_in, const float* __restrict__ Wd,
                          const float* __restrict__ W_ih, const float* __restrict__ W_hh,
                          float* __restrict__ WinT, float* __restrict__ WdT0,
                          float* __restrict__ WdT1, float* __restrict__ WihT,
                          float* __restrict__ WhhT) {
  int i = blockIdx.x * 256 + threadIdx.x;
  if (i < 16384) { int r = i >> 7, c = i & 127; WinT[c * 128 + r] = W_in[i]; return; }
  i -= 16384;
  if (i < 32768) { int r = i >> 8, c = i & 255; WdT0[c * 128 + r] = Wd[i]; return; }
  i -= 32768;
  if (i < 32768) { int r = i >> 8, c = i & 255; WdT1[c * 128 + r] = Wd[32768 + i]; return; }
  i -= 32768;
  if (i < 49152) { int r = i >> 7, c = i & 127; WihT[c * 384 + r] = W_ih[i]; return; }
  i -= 49152;
  if (i < 49152) { int r = i >> 7, c = i & 127; WhhT[c * 384 + r] = W_hh[i]; }
}

// ======== deterministic two-pass bucket scatter (NO global atomics) ========
__global__ __launch_bounds__(256)
void ecount_kernel(const int* __restrict__ row, int* __restrict__ countsT,
                   int E, int nbuck) {
  __shared__ int lh[1024];
  int b = blockIdx.x;
  for (int i = threadIdx.x; i < nbuck; i += 256) lh[i] = 0;
  __syncthreads();
  int per = (E + NSB - 1) / NSB;
  int s = b * per, e = min(s + per, E);
  for (int i = s + (int)threadIdx.x; i < e; i += 256)
    atomicAdd(&lh[row[i] >> BSHIFT], 1);   // LDS atomic, shallow
  __syncthreads();
  for (int i = threadIdx.x; i < nbuck; i += 256) countsT[i * NSB + b] = lh[i];
}

__global__ __launch_bounds__(NSB)
void bprefix_kernel(int* __restrict__ countsT, int* __restrict__ btotal, int nbuck) {
  __shared__ int sd[NSB];
  int bk = blockIdx.x;
  int t = threadIdx.x;
  int v = countsT[bk * NSB + t];
  sd[t] = v;
  __syncthreads();
  for (int off = 1; off < NSB; off <<= 1) {
    int u = (t >= off) ? sd[t - off] : 0;
    __syncthreads();
    sd[t] += u;
    __syncthreads();
  }
  countsT[bk * NSB + t] = sd[t] - v;       // exclusive within bucket
  if (t == NSB - 1) btotal[bk] = sd[t];
}

__global__ __launch_bounds__(1024)
void bstart_kernel(const int* __restrict__ btotal, int* __restrict__ bstart,
                   int* __restrict__ offsets, int N, int nbuck) {
  __shared__ int sd[1024];
  int t = threadIdx.x;
  int v = (t < nbuck) ? btotal[t] : 0;
  sd[t] = v;
  __syncthreads();
  for (int off = 1; off < 1024; off <<= 1) {
    int u = (t >= off) ? sd[t - off] : 0;
    __syncthreads();
    sd[t] += u;
    __syncthreads();
  }
  if (t < nbuck) bstart[t] = sd[t] - v;
  if (t == nbuck - 1) { bstart[nbuck] = sd[t]; offsets[N] = sd[t]; }
}

__global__ __launch_bounds__(256)
void escatter_kernel(const int* __restrict__ row, const int* __restrict__ col,
                     const int* __restrict__ countsT, const int* __restrict__ bstart,
                     int2* __restrict__ ebuf, int E, int nbuck) {
  __shared__ int lcur[1024];
  int b = blockIdx.x;
  for (int i = threadIdx.x; i < nbuck; i += 256)
    lcur[i] = bstart[i] + countsT[i * NSB + b];
  __syncthreads();
  int per = (E + NSB - 1) / NSB;
  int s = b * per, e = min(s + per, E);
  for (int i = s + (int)threadIdx.x; i < e; i += 256) {
    int r = row[i], c = col[i];
    int pos = atomicAdd(&lcur[r >> BSHIFT], 1);
    ebuf[pos] = make_int2(r, c);
  }
}

// pass 3: per-bucket LDS counting sort by row -> CSR (offsets + csrcol).
// DETERMINISM FIX (round 9 failed replay-consistency): after scattering a
// bucket's cols into LDS windows (atomic order = nondeterministic), each node's
// window is insertion-SORTED BY COL. Ties are identical col ids -> identical
// |h_r-h_c| values -> sums bit-identical regardless of duplicate placement.
// This makes diff/tau/mask bit-stable across launches; round-9's 16.9 post-
// timing divergence was a knife-edge tau (~0.005) node flipping its GRU mask
// under atomic-order jitter.
__global__ __launch_bounds__(256)
void bsort_kernel(const int2* __restrict__ ebuf, const int* __restrict__ bstart,
                  int* __restrict__ offsets, int* __restrict__ csr_col,
                  int N, int nbuck) {
  __shared__ int cnt[128], off[128], cur[128];
  __shared__ int lcol[MAXB];
  int bk = blockIdx.x;
  int tid = threadIdx.x;
  int s = bstart[bk], e = bstart[bk + 1];
  int m = e - s;
  if (tid < 128) cnt[tid] = 0;
  __syncthreads();
  for (int i = s + tid; i < e; i += 256)
    atomicAdd(&cnt[ebuf[i].x & 127], 1);
  __syncthreads();
  if (tid < 128) off[tid] = cnt[tid];
  __syncthreads();
  for (int d = 1; d < 128; d <<= 1) {
    int v = 0;
    if (tid < 128 && tid >= d) v = off[tid - d];
    __syncthreads();
    if (tid < 128) off[tid] += v;
    __syncthreads();
  }
  if (tid < 128) {
    cur[tid] = off[tid] - cnt[tid];          // local exclusive
    int node = (bk << BSHIFT) + tid;
    if (node < N) offsets[node] = s + off[tid] - cnt[tid];
  }
  __syncthreads();
  if (m <= MAXB) {
    for (int i = s + tid; i < e; i += 256) {
      int2 rc = ebuf[i];
      int pos = atomicAdd(&cur[rc.x & 127], 1);   // local pos
      lcol[pos] = rc.y;
    }
    __syncthreads();
    if (tid < 128) {                               // per-node sort by col
      int b0 = off[tid] - cnt[tid], b1 = off[tid];
      for (int i = b0 + 1; i < b1; ++i) {
        int key = lcol[i];
        int j = i - 1;
        while (j >= b0 && lcol[j] > key) { lcol[j + 1] = lcol[j]; --j; }
        lcol[j + 1] = key;
      }
    }
    __syncthreads();
    for (int i = tid; i < m; i += 256) csr_col[s + i] = lcol[i];
  } else {
    // fallback (never expected for this data): unsorted direct scatter
    for (int i = s + tid; i < e; i += 256) {
      int2 rc = ebuf[i];
      int pos = atomicAdd(&cur[rc.x & 127], 1);
      csr_col[s + pos] = rc.y;
    }
  }
}

// ---------------- edge aggregation: diff[i][d] = sum_e |h[i][d]-h[col][d]| ----
// One wave per node; lane owns dims {2l, 2l+1} (float2/dwordx2 gathers).
// Register accumulation; 8-edge unroll = 8 outstanding 8B gathers/lane.
__global__ __launch_bounds__(256)
void aggregate_kernel(const float* __restrict__ h, const int* __restrict__ offsets,
                      const int* __restrict__ csr_col, float* __restrict__ diff,
                      int N) {
  int wave = threadIdx.x >> 6;
  int lane = threadIdx.x & 63;
  int node = blockIdx.x * 4 + wave;
  if (node >= N) return;
  int start = offsets[node], end = offsets[node + 1];
  int deg = end - start;
  const float2* hrow = (const float2*)(h + (size_t)node * HID);
  float2 hv = hrow[lane];
  float a0 = 0.f, a1 = 0.f;

  int batch = min(deg, 64);
  int myc = (lane < batch) ? csr_col[start + lane] : 0;
  int j = 0;
  for (; j + 8 <= batch; j += 8) {
    const float2* p0 = (const float2*)(h + (size_t)__shfl(myc, j + 0) * HID);
    const float2* p1 = (const float2*)(h + (size_t)__shfl(myc, j + 1) * HID);
    const float2* p2 = (const float2*)(h + (size_t)__shfl(myc, j + 2) * HID);
    const float2* p3 = (const float2*)(h + (size_t)__shfl(myc, j + 3) * HID);
    const float2* p4 = (const float2*)(h + (size_t)__shfl(myc, j + 4) * HID);
    const float2* p5 = (const float2*)(h + (size_t)__shfl(myc, j + 5) * HID);
    const float2* p6 = (const float2*)(h + (size_t)__shfl(myc, j + 6) * HID);
    const float2* p7 = (const float2*)(h + (size_t)__shfl(myc, j + 7) * HID);
    float2 x0 = p0[lane], x1 = p1[lane], x2 = p2[lane], x3 = p3[lane];
    float2 x4 = p4[lane], x5 = p5[lane], x6 = p6[lane], x7 = p7[lane];
    a0 += fabsf(hv.x - x0.x) + fabsf(hv.x - x1.x) + fabsf(hv.x - x2.x) + fabsf(hv.x - x3.x)
        + fabsf(hv.x - x4.x) + fabsf(hv.x - x5.x) + fabsf(hv.x - x6.x) + fabsf(hv.x - x7.x);
    a1 += fabsf(hv.y - x0.y) + fabsf(hv.y - x1.y) + fabsf(hv.y - x2.y) + fabsf(hv.y - x3.y)
        + fabsf(hv.y - x4.y) + fabsf(hv.y - x5.y) + fabsf(hv.y - x6.y) + fabsf(hv.y - x7.y);
  }
  for (; j < batch; ++j) {
    const float2* p = (const float2*)(h + (size_t)__shfl(myc, j) * HID);
    float2 x = p[lane];
    a0 += fabsf(hv.x - x.x);
    a1 += fabsf(hv.y - x.y);
  }
  for (int e = start + 64; e < end; ++e) {
    const float2* p = (const float2*)(h + (size_t)csr_col[e] * HID);
    float2 x = p[lane];
    a0 += fabsf(hv.x - x.x);
    a1 += fabsf(hv.y - x.y);
  }
  *(float2*)(diff + (size_t)node * HID + 2 * lane) = make_float2(a0, a1);
}

// ---------------- tiled fp32 GEMM: C = relu([A1|A2] @ BT + bias), opt tau ----
// 512 threads/block, 8x4 acc/thread (24 waves/CU). TAU epilogue also does
// mask-compaction (list membership deterministic; list ORDER nondeterministic
// but GRU output is order-independent).
template<bool TAU>
__global__ __launch_bounds__(512)
void gemm_kernel(const float* __restrict__ A1, const float* __restrict__ A2,
                 const float* __restrict__ BT, const float* __restrict__ bias,
                 float* __restrict__ C, int M, int nchunks,
                 const float* __restrict__ Wt, const float* __restrict__ bt,
                 float* __restrict__ tau_out, int* __restrict__ mlist,
                 int* __restrict__ mcount) {
  __shared__ float As[32][132];   // [k][i], padded leading dim
  __shared__ float Bs[32][128];   // [k][c]
  __shared__ float taured[128];
  int tid = threadIdx.x;
  int tx = tid & 31;   // col group: cols tx + 32*u, u<4
  int ty = tid >> 5;   // row group: rows ty*8 + r, r<8 (ty in 0..15)
  int i0 = blockIdx.x * 128;
  float acc[8][4] = {};

  for (int kc = 0; kc < nchunks; ++kc) {
    const float* A = (kc < 4) ? A1 : A2;
    int ksrc = (kc & 3) * 32;
    int kglob = kc * 32;
    #pragma unroll
    for (int q = 0; q < 2; ++q) {     // stage A (transposed into LDS)
      int f = q * 512 + tid;
      int i = f >> 3;
      int kq = (f & 7) << 2;
      int ig = i0 + i; if (ig >= M) ig = M - 1;
      float4 v = *(const float4*)(A + (size_t)ig * HID + ksrc + kq);
      As[kq + 0][i] = v.x; As[kq + 1][i] = v.y;
      As[kq + 2][i] = v.z; As[kq + 3][i] = v.w;
    }
    #pragma unroll
    for (int q = 0; q < 2; ++q) {     // stage B
      int f = q * 512 + tid;
      int k = f >> 5; int c4 = (f & 31) << 2;
      *(float4*)&Bs[k][c4] = *(const float4*)(BT + (size_t)(kglob + k) * HID + c4);
    }
    __syncthreads();
    #pragma unroll
    for (int k = 0; k < 32; ++k) {
      float a[8], b[4];
      const float4* ap = (const float4*)&As[k][ty * 8];
      float4 a0 = ap[0], a1 = ap[1];
      a[0]=a0.x; a[1]=a0.y; a[2]=a0.z; a[3]=a0.w;
      a[4]=a1.x; a[5]=a1.y; a[6]=a1.z; a[7]=a1.w;
      #pragma unroll
      for (int u = 0; u < 4; ++u) b[u] = Bs[k][tx + 32 * u];
      #pragma unroll
      for (int r = 0; r < 8; ++r)
        #pragma unroll
        for (int u = 0; u < 4; ++u)
          acc[r][u] = fmaf(a[r], b[u], acc[r][u]);
    }
    __syncthreads();
  }

  float bias_r[4], wt_r[4];
  #pragma unroll
  for (int u = 0; u < 4; ++u) { bias_r[u] = bias[tx + 32 * u]; wt_r[u] = 0.f; }
  if constexpr (TAU) {
    #pragma unroll
    for (int u = 0; u < 4; ++u) wt_r[u] = Wt[tx + 32 * u];
  }
  #pragma unroll
  for (int r = 0; r < 8; ++r) {
    int row = i0 + ty * 8 + r;
    bool ok = row < M;
    float p = 0.f;
    #pragma unroll
    for (int u = 0; u < 4; ++u) {
      float v = fmaxf(acc[r][u] + bias_r[u], 0.f);
      if (ok) C[(size_t)row * HID + tx + 32 * u] = v;
      p = fmaf(v, wt_r[u], p);
    }
    if constexpr (TAU) {
      p += __shfl_down(p, 16, 32);
      p += __shfl_down(p, 8, 32);
      p += __shfl_down(p, 4, 32);
      p += __shfl_down(p, 2, 32);
      p += __shfl_down(p, 1, 32);
      if (tx == 0) taured[ty * 8 + r] = p;
    }
  }
  if constexpr (TAU) {
    __syncthreads();
    if (tid < 128) {
      int row = i0 + tid;
      if (row < M) {
        float pre = taured[tid] + bt[0];
        float tau = (pre > 20.f) ? pre : log1pf(expf(pre));
        tau_out[row] = tau;
        // np semantics: floor(1/tau).astype(int32) overflows to INT_MIN for
        // 1/tau >= 2^31 -> n_updates <= 0 -> NOT masked even though tau<0.005.
        if (tau < 0.005f && (1.0f / tau) < 2147483648.0f) {
          int pos = atomicAdd(mcount, 1);
          mlist[pos] = row;
        }
      }
    }
  }
}

// ---------------- masked GRU, 32 nodes / block (512 threads) ----------------
__global__ __launch_bounds__(512)
void gru_kernel(const float* __restrict__ diff, float* __restrict__ h,
                const int* __restrict__ list, const int* __restrict__ count,
                const float* __restrict__ WihT, const float* __restrict__ WhhT,
                const float* __restrict__ b_ih, const float* __restrict__ b_hh) {
  int cnt = *count;
  int base = blockIdx.x * 32;
  if (base >= cnt) return;
  __shared__ float dl[32][HID];
  __shared__ float hl[32][HID];
  __shared__ int ids[32];
  int tid = threadIdx.x;
  if (tid < 32) ids[tid] = (base + tid < cnt) ? list[base + tid] : -1;
  __syncthreads();
  #pragma unroll
  for (int q = 0; q < 8; ++q) {
    int f = q * 512 + tid;
    int r = f >> 7, c = f & 127;
    int id = ids[r];
    int src = (id >= 0) ? id : 0;
    dl[r][c] = diff[(size_t)src * HID + c];
    hl[r][c] = h[(size_t)src * HID + c];
  }
  __syncthreads();
  int tx = tid & 127, ty = tid >> 7;   // ty in 0..3 -> rows ty*8..ty*8+7
  float air[8] = {}, aiz[8] = {}, ain[8] = {}, ahr[8] = {}, ahz[8] = {}, ahn[8] = {};
  for (int k = 0; k < HID; ++k) {
    float wir = WihT[k * 384 + tx];
    float wiz = WihT[k * 384 + 128 + tx];
    float win = WihT[k * 384 + 256 + tx];
    float whr = WhhT[k * 384 + tx];
    float whz = WhhT[k * 384 + 128 + tx];
    float whn = WhhT[k * 384 + 256 + tx];
    #pragma unroll
    for (int r = 0; r < 8; ++r) {
      float dk = dl[ty * 8 + r][k];
      float hk = hl[ty * 8 + r][k];
      air[r] = fmaf(dk, wir, air[r]);
      aiz[r] = fmaf(dk, wiz, aiz[r]);
      ain[r] = fmaf(dk, win, ain[r]);
      ahr[r] = fmaf(hk, whr, ahr[r]);
      ahz[r] = fmaf(hk, whz, ahz[r]);
      ahn[r] = fmaf(hk, whn, ahn[r]);
    }
  }
  float bir = b_ih[tx], biz = b_ih[128 + tx], bin = b_ih[256 + tx];
  float bhr = b_hh[tx], bhz = b_hh[128 + tx], bhn = b_hh[256 + tx];
  #pragma unroll
  for (int r = 0; r < 8; ++r) {
    int id = ids[ty * 8 + r];
    if (id < 0) continue;
    float rg = 1.f / (1.f + expf(-((air[r] + bir) + (ahr[r] + bhr))));
    float z  = 1.f / (1.f + expf(-((aiz[r] + biz) + (ahz[r] + bhz))));
    float n  = tanhf((ain[r] + bin) + rg * (ahn[r] + bhn));
    float hv = hl[ty * 8 + r][tx];
    h[(size_t)id * HID + tx] = (1.f - z) * n + z * hv;
  }
}

// ---------------- output head: out = h @ Wo^T + bo  (wave per node) ----------
__global__ void out_kernel(const float* __restrict__ h, const float* __restrict__ Wo,
                           const float* __restrict__ bo, float* __restrict__ out, int N) {
  int g = blockIdx.x * blockDim.x + threadIdx.x;
  int node = g >> 6;
  int lane = threadIdx.x & 63;
  if (node >= N) return;
  float h0 = h[(size_t)node * HID + lane];
  float h1 = h[(size_t)node * HID + 64 + lane];
  float s0 = h0 * Wo[lane] + h1 * Wo[64 + lane];
  float s1 = h0 * Wo[128 + lane] + h1 * Wo[192 + lane];
  for (int d = 32; d; d >>= 1) {
    s0 += __shfl_down(s0, d);
    s1 += __shfl_down(s1, d);
  }
  if (lane == 0) {
    out[(size_t)node * 2 + 0] = s0 + bo[0];
    out[(size_t)node * 2 + 1] = s1 + bo[1];
  }
}

extern "C" void kernel_launch(void* const* d_in, const int* in_sizes, int n_in,
                              void* d_out, int out_size, void* d_ws, size_t ws_size,
                              hipStream_t stream) {
  const float* x    = (const float*)d_in[0];
  const int*   ei   = (const int*)d_in[1];
  const float* W_in = (const float*)d_in[2];
  const float* b_in = (const float*)d_in[3];
  const float* Wd   = (const float*)d_in[4];
  const float* bd   = (const float*)d_in[5];
  const float* Wt   = (const float*)d_in[6];
  const float* bt   = (const float*)d_in[7];
  const float* W_ih = (const float*)d_in[8];
  const float* W_hh = (const float*)d_in[9];
  const float* b_ih = (const float*)d_in[10];
  const float* b_hh = (const float*)d_in[11];
  const float* Wo   = (const float*)d_in[12];
  const float* bo   = (const float*)d_in[13];

  const int N = in_sizes[0] / HID;      // 100000
  const int E = in_sizes[1] / 2;        // 1600000
  const int* rowp = ei;
  const int* colp = ei + E;
  const int nbuck = (N + (1 << BSHIFT) - 1) >> BSHIFT;   // 782 (<=1024)

  // workspace carve-up (256B aligned)
  char* p = (char*)d_ws;
  auto alloc = [&](size_t bytes) { void* r = (void*)p; p += (bytes + 255) & ~(size_t)255; return r; };
  float* hA     = (float*)alloc((size_t)N * HID * 4);
  float* hB     = (float*)alloc((size_t)N * HID * 4);
  float* diff   = (float*)alloc((size_t)N * HID * 4);
  float* WinT   = (float*)alloc(128 * 128 * 4);
  float* WdT0   = (float*)alloc(256 * 128 * 4);
  float* WdT1   = (float*)alloc(256 * 128 * 4);
  float* WihT   = (float*)alloc(128 * 384 * 4);
  float* WhhT   = (float*)alloc(128 * 384 * 4);
  float* tau0   = (float*)alloc((size_t)N * 4);
  int*   list   = (int*)alloc((size_t)N * 4);
  int*   count  = (int*)alloc(256);
  int*   countsT= (int*)alloc((size_t)1024 * NSB * 4);
  int*   btotal = (int*)alloc(1024 * 4);
  int*   bstart = (int*)alloc(1028 * 4);
  int*   offs   = (int*)alloc(((size_t)N + 1) * 4);
  int*   csrcol = (int*)alloc((size_t)E * 4);
  int2*  ebuf   = (int2*)alloc((size_t)E * 8);

  float* out_ptr = (float*)d_out;            // [N,2] flat
  float* tau_out = (float*)d_out + (size_t)N * 2;  // [N]

  // zero both layers' mask counters (ws is poisoned before every launch)
  hipMemsetAsync(count, 0, 8, stream);

  // fused weight transposes (1 launch)
  transpose_all_kernel<<<(180224 + 255) / 256, 256, 0, stream>>>(
      W_in, Wd, W_ih, W_hh, WinT, WdT0, WdT1, WihT, WhhT);

  // CSR build, no global atomics, DETERMINISTIC csrcol (reused by both layers)
  ecount_kernel<<<NSB, 256, 0, stream>>>(rowp, countsT, E, nbuck);
  bprefix_kernel<<<nbuck, NSB, 0, stream>>>(countsT, btotal, nbuck);
  bstart_kernel<<<1, 1024, 0, stream>>>(btotal, bstart, offs, N, nbuck);
  escatter_kernel<<<NSB, 256, 0, stream>>>(rowp, colp, countsT, bstart, ebuf, E, nbuck);
  bsort_kernel<<<nbuck, 256, 0, stream>>>(ebuf, bstart, offs, csrcol, N, nbuck);

  const int gemm_blocks = (N + 127) / 128;
  const int agg_blocks = (N + 3) / 4;
  const int gru_blocks = (N + 31) / 32;

  // input layer: hA = relu(x @ Win^T + b_in)
  gemm_kernel<false><<<gemm_blocks, 512, 0, stream>>>(
      x, nullptr, WinT, b_in, hA, N, 4, nullptr, nullptr, nullptr, nullptr, nullptr);

  // ---- layer 0 ----
  aggregate_kernel<<<agg_blocks, 256, 0, stream>>>(hA, offs, csrcol, diff, N);
  gemm_kernel<true><<<gemm_blocks, 512, 0, stream>>>(
      hA, diff, WdT0, bd, hB, N, 8, Wt, bt, tau0, list, count);
  gru_kernel<<<gru_blocks, 512, 0, stream>>>(diff, hB, list, count, WihT, WhhT, b_ih, b_hh);

  // ---- layer 1 ----
  aggregate_kernel<<<agg_blocks, 256, 0, stream>>>(hB, offs, csrcol, diff, N);
  gemm_kernel<true><<<gemm_blocks, 512, 0, stream>>>(
      hB, diff, WdT1, bd + 128, hA, N, 8, Wt, bt, tau_out, list, count + 1);
  gru_kernel<<<gru_blocks, 512, 0, stream>>>(diff, hA, list, count + 1, WihT, WhhT, b_ih, b_hh);

  // output head
  out_kernel<<<((size_t)N * 64 + 255) / 256, 256, 0, stream>>>(hA, Wo, bo, out_ptr, N);
}

// Round 11
// 764.161 us; speedup vs baseline: 1.0222x; 1.0222x over previous
//
#include <hip/hip_runtime.h>
#include <cstdint>
#include <cstddef>

#define HID 128
#define BSHIFT 7            // 128 nodes per bucket -> nbuck = 782 for N=100000
#define NSB 256             // scatter blocks (pass1/pass2 chunking)
#define MAXB 4096           // LDS sort capacity (avg bucket = 2046 edges)

// ======== deterministic two-pass bucket scatter (NO global atomics) ========
// ecount also absorbs the 5 weight transposes (grid-stride prelude; saves a
// dispatch — the transposes are independent of edge data).
__global__ __launch_bounds__(256)
void ecount_kernel(const int* __restrict__ row, int* __restrict__ countsT,
                   int E, int nbuck,
                   const float* __restrict__ W_in, const float* __restrict__ Wd,
                   const float* __restrict__ W_ih, const float* __restrict__ W_hh,
                   float* __restrict__ WinT, float* __restrict__ WdT0,
                   float* __restrict__ WdT1, float* __restrict__ WihT,
                   float* __restrict__ WhhT) {
  // --- transpose prelude (180224 elements over 65536 threads) ---
  for (int i = blockIdx.x * 256 + threadIdx.x; i < 180224; i += NSB * 256) {
    int j = i;
    if (j < 16384) { int r = j >> 7, c = j & 127; WinT[c * 128 + r] = W_in[j]; continue; }
    j -= 16384;
    if (j < 32768) { int r = j >> 8, c = j & 255; WdT0[c * 128 + r] = Wd[j]; continue; }
    j -= 32768;
    if (j < 32768) { int r = j >> 8, c = j & 255; WdT1[c * 128 + r] = Wd[32768 + j]; continue; }
    j -= 32768;
    if (j < 49152) { int r = j >> 7, c = j & 127; WihT[c * 384 + r] = W_ih[j]; continue; }
    j -= 49152;
    { int r = j >> 7, c = j & 127; WhhT[c * 384 + r] = W_hh[j]; }
  }
  // --- bucket histogram ---
  __shared__ int lh[1024];
  int b = blockIdx.x;
  for (int i = threadIdx.x; i < nbuck; i += 256) lh[i] = 0;
  __syncthreads();
  int per = (E + NSB - 1) / NSB;
  int s = b * per, e = min(s + per, E);
  for (int i = s + (int)threadIdx.x; i < e; i += 256)
    atomicAdd(&lh[row[i] >> BSHIFT], 1);   // LDS atomic, shallow
  __syncthreads();
  for (int i = threadIdx.x; i < nbuck; i += 256) countsT[i * NSB + b] = lh[i];
}

__global__ __launch_bounds__(NSB)
void bprefix_kernel(int* __restrict__ countsT, int* __restrict__ btotal, int nbuck) {
  __shared__ int sd[NSB];
  int bk = blockIdx.x;
  int t = threadIdx.x;
  int v = countsT[bk * NSB + t];
  sd[t] = v;
  __syncthreads();
  for (int off = 1; off < NSB; off <<= 1) {
    int u = (t >= off) ? sd[t - off] : 0;
    __syncthreads();
    sd[t] += u;
    __syncthreads();
  }
  countsT[bk * NSB + t] = sd[t] - v;       // exclusive within bucket
  if (t == NSB - 1) btotal[bk] = sd[t];
}

__global__ __launch_bounds__(1024)
void bstart_kernel(const int* __restrict__ btotal, int* __restrict__ bstart,
                   int* __restrict__ offsets, int N, int nbuck) {
  __shared__ int sd[1024];
  int t = threadIdx.x;
  int v = (t < nbuck) ? btotal[t] : 0;
  sd[t] = v;
  __syncthreads();
  for (int off = 1; off < 1024; off <<= 1) {
    int u = (t >= off) ? sd[t - off] : 0;
    __syncthreads();
    sd[t] += u;
    __syncthreads();
  }
  if (t < nbuck) bstart[t] = sd[t] - v;
  if (t == nbuck - 1) { bstart[nbuck] = sd[t]; offsets[N] = sd[t]; }
}

__global__ __launch_bounds__(256)
void escatter_kernel(const int* __restrict__ row, const int* __restrict__ col,
                     const int* __restrict__ countsT, const int* __restrict__ bstart,
                     int2* __restrict__ ebuf, int E, int nbuck) {
  __shared__ int lcur[1024];
  int b = blockIdx.x;
  for (int i = threadIdx.x; i < nbuck; i += 256)
    lcur[i] = bstart[i] + countsT[i * NSB + b];
  __syncthreads();
  int per = (E + NSB - 1) / NSB;
  int s = b * per, e = min(s + per, E);
  for (int i = s + (int)threadIdx.x; i < e; i += 256) {
    int r = row[i], c = col[i];
    int pos = atomicAdd(&lcur[r >> BSHIFT], 1);
    ebuf[pos] = make_int2(r, c);
  }
}

// pass 3: per-bucket LDS counting sort by row -> CSR (offsets + csrcol).
// DETERMINISM: each node's window is insertion-sorted by col; ties are
// identical values -> diff/tau/mask bit-stable across launches (round-9 fix).
__global__ __launch_bounds__(256)
void bsort_kernel(const int2* __restrict__ ebuf, const int* __restrict__ bstart,
                  int* __restrict__ offsets, int* __restrict__ csr_col,
                  int N, int nbuck) {
  __shared__ int cnt[128], off[128], cur[128];
  __shared__ int lcol[MAXB];
  int bk = blockIdx.x;
  int tid = threadIdx.x;
  int s = bstart[bk], e = bstart[bk + 1];
  int m = e - s;
  if (tid < 128) cnt[tid] = 0;
  __syncthreads();
  for (int i = s + tid; i < e; i += 256)
    atomicAdd(&cnt[ebuf[i].x & 127], 1);
  __syncthreads();
  if (tid < 128) off[tid] = cnt[tid];
  __syncthreads();
  for (int d = 1; d < 128; d <<= 1) {
    int v = 0;
    if (tid < 128 && tid >= d) v = off[tid - d];
    __syncthreads();
    if (tid < 128) off[tid] += v;
    __syncthreads();
  }
  if (tid < 128) {
    cur[tid] = off[tid] - cnt[tid];          // local exclusive
    int node = (bk << BSHIFT) + tid;
    if (node < N) offsets[node] = s + off[tid] - cnt[tid];
  }
  __syncthreads();
  if (m <= MAXB) {
    for (int i = s + tid; i < e; i += 256) {
      int2 rc = ebuf[i];
      int pos = atomicAdd(&cur[rc.x & 127], 1);   // local pos
      lcol[pos] = rc.y;
    }
    __syncthreads();
    if (tid < 128) {                               // per-node sort by col
      int b0 = off[tid] - cnt[tid], b1 = off[tid];
      for (int i = b0 + 1; i < b1; ++i) {
        int key = lcol[i];
        int j = i - 1;
        while (j >= b0 && lcol[j] > key) { lcol[j + 1] = lcol[j]; --j; }
        lcol[j + 1] = key;
      }
    }
    __syncthreads();
    for (int i = tid; i < m; i += 256) csr_col[s + i] = lcol[i];
  } else {
    // fallback (never expected for this data): unsorted direct scatter
    for (int i = s + tid; i < e; i += 256) {
      int2 rc = ebuf[i];
      int pos = atomicAdd(&cur[rc.x & 127], 1);
      csr_col[s + pos] = rc.y;
    }
  }
}

// ---------------- edge aggregation: diff[i][d] = sum_e |h[i][d]-h[col][d]| ----
// One wave per node; lane owns dims {2l, 2l+1} (float2/dwordx2 gathers).
// 16-edge load batching (two 8-groups in flight = 16 outstanding 8B gathers)
// with summation order identical to consecutive 8-groups (bit-identical diff).
// Backend-bound check: FETCH = 8 XCD x 51 MB (each L2 fetches h once) at
// ~3.4 TB/s L3->L2 fill; if this change is neutral the ceiling is confirmed.
__global__ __launch_bounds__(256)
void aggregate_kernel(const float* __restrict__ h, const int* __restrict__ offsets,
                      const int* __restrict__ csr_col, float* __restrict__ diff,
                      int N) {
  int wave = threadIdx.x >> 6;
  int lane = threadIdx.x & 63;
  int node = blockIdx.x * 4 + wave;
  if (node >= N) return;
  int start = offsets[node], end = offsets[node + 1];
  int deg = end - start;
  const float2* hrow = (const float2*)(h + (size_t)node * HID);
  float2 hv = hrow[lane];
  float a0 = 0.f, a1 = 0.f;

  int batch = min(deg, 64);
  int myc = (lane < batch) ? csr_col[start + lane] : 0;
  int j = 0;
  for (; j + 16 <= batch; j += 16) {
    const float2* p0 = (const float2*)(h + (size_t)__shfl(myc, j + 0) * HID);
    const float2* p1 = (const float2*)(h + (size_t)__shfl(myc, j + 1) * HID);
    const float2* p2 = (const float2*)(h + (size_t)__shfl(myc, j + 2) * HID);
    const float2* p3 = (const float2*)(h + (size_t)__shfl(myc, j + 3) * HID);
    const float2* p4 = (const float2*)(h + (size_t)__shfl(myc, j + 4) * HID);
    const float2* p5 = (const float2*)(h + (size_t)__shfl(myc, j + 5) * HID);
    const float2* p6 = (const float2*)(h + (size_t)__shfl(myc, j + 6) * HID);
    const float2* p7 = (const float2*)(h + (size_t)__shfl(myc, j + 7) * HID);
    const float2* q0 = (const float2*)(h + (size_t)__shfl(myc, j + 8) * HID);
    const float2* q1 = (const float2*)(h + (size_t)__shfl(myc, j + 9) * HID);
    const float2* q2 = (const float2*)(h + (size_t)__shfl(myc, j + 10) * HID);
    const float2* q3 = (const float2*)(h + (size_t)__shfl(myc, j + 11) * HID);
    const float2* q4 = (const float2*)(h + (size_t)__shfl(myc, j + 12) * HID);
    const float2* q5 = (const float2*)(h + (size_t)__shfl(myc, j + 13) * HID);
    const float2* q6 = (const float2*)(h + (size_t)__shfl(myc, j + 14) * HID);
    const float2* q7 = (const float2*)(h + (size_t)__shfl(myc, j + 15) * HID);
    float2 x0 = p0[lane], x1 = p1[lane], x2 = p2[lane], x3 = p3[lane];
    float2 x4 = p4[lane], x5 = p5[lane], x6 = p6[lane], x7 = p7[lane];
    float2 y0 = q0[lane], y1 = q1[lane], y2 = q2[lane], y3 = q3[lane];
    float2 y4 = q4[lane], y5 = q5[lane], y6 = q6[lane], y7 = q7[lane];
    a0 += fabsf(hv.x - x0.x) + fabsf(hv.x - x1.x) + fabsf(hv.x - x2.x) + fabsf(hv.x - x3.x)
        + fabsf(hv.x - x4.x) + fabsf(hv.x - x5.x) + fabsf(hv.x - x6.x) + fabsf(hv.x - x7.x);
    a1 += fabsf(hv.y - x0.y) + fabsf(hv.y - x1.y) + fabsf(hv.y - x2.y) + fabsf(hv.y - x3.y)
        + fabsf(hv.y - x4.y) + fabsf(hv.y - x5.y) + fabsf(hv.y - x6.y) + fabsf(hv.y - x7.y);
    a0 += fabsf(hv.x - y0.x) + fabsf(hv.x - y1.x) + fabsf(hv.x - y2.x) + fabsf(hv.x - y3.x)
        + fabsf(hv.x - y4.x) + fabsf(hv.x - y5.x) + fabsf(hv.x - y6.x) + fabsf(hv.x - y7.x);
    a1 += fabsf(hv.y - y0.y) + fabsf(hv.y - y1.y) + fabsf(hv.y - y2.y) + fabsf(hv.y - y3.y)
        + fabsf(hv.y - y4.y) + fabsf(hv.y - y5.y) + fabsf(hv.y - y6.y) + fabsf(hv.y - y7.y);
  }
  for (; j + 8 <= batch; j += 8) {
    const float2* p0 = (const float2*)(h + (size_t)__shfl(myc, j + 0) * HID);
    const float2* p1 = (const float2*)(h + (size_t)__shfl(myc, j + 1) * HID);
    const float2* p2 = (const float2*)(h + (size_t)__shfl(myc, j + 2) * HID);
    const float2* p3 = (const float2*)(h + (size_t)__shfl(myc, j + 3) * HID);
    const float2* p4 = (const float2*)(h + (size_t)__shfl(myc, j + 4) * HID);
    const float2* p5 = (const float2*)(h + (size_t)__shfl(myc, j + 5) * HID);
    const float2* p6 = (const float2*)(h + (size_t)__shfl(myc, j + 6) * HID);
    const float2* p7 = (const float2*)(h + (size_t)__shfl(myc, j + 7) * HID);
    float2 x0 = p0[lane], x1 = p1[lane], x2 = p2[lane], x3 = p3[lane];
    float2 x4 = p4[lane], x5 = p5[lane], x6 = p6[lane], x7 = p7[lane];
    a0 += fabsf(hv.x - x0.x) + fabsf(hv.x - x1.x) + fabsf(hv.x - x2.x) + fabsf(hv.x - x3.x)
        + fabsf(hv.x - x4.x) + fabsf(hv.x - x5.x) + fabsf(hv.x - x6.x) + fabsf(hv.x - x7.x);
    a1 += fabsf(hv.y - x0.y) + fabsf(hv.y - x1.y) + fabsf(hv.y - x2.y) + fabsf(hv.y - x3.y)
        + fabsf(hv.y - x4.y) + fabsf(hv.y - x5.y) + fabsf(hv.y - x6.y) + fabsf(hv.y - x7.y);
  }
  for (; j < batch; ++j) {
    const float2* p = (const float2*)(h + (size_t)__shfl(myc, j) * HID);
    float2 x = p[lane];
    a0 += fabsf(hv.x - x.x);
    a1 += fabsf(hv.y - x.y);
  }
  for (int e = start + 64; e < end; ++e) {
    const float2* p = (const float2*)(h + (size_t)csr_col[e] * HID);
    float2 x = p[lane];
    a0 += fabsf(hv.x - x.x);
    a1 += fabsf(hv.y - x.y);
  }
  *(float2*)(diff + (size_t)node * HID + 2 * lane) = make_float2(a0, a1);
}

// ---------------- tiled fp32 GEMM: C = relu([A1|A2] @ BT + bias), opt tau ----
// 512 threads/block, 8x4 acc/thread (24 waves/CU). TAU epilogue also does
// mask-compaction (list membership deterministic; list order irrelevant to GRU).
template<bool TAU>
__global__ __launch_bounds__(512)
void gemm_kernel(const float* __restrict__ A1, const float* __restrict__ A2,
                 const float* __restrict__ BT, const float* __restrict__ bias,
                 float* __restrict__ C, int M, int nchunks,
                 const float* __restrict__ Wt, const float* __restrict__ bt,
                 float* __restrict__ tau_out, int* __restrict__ mlist,
                 int* __restrict__ mcount) {
  __shared__ float As[32][132];   // [k][i], padded leading dim
  __shared__ float Bs[32][128];   // [k][c]
  __shared__ float taured[128];
  int tid = threadIdx.x;
  int tx = tid & 31;   // col group: cols tx + 32*u, u<4
  int ty = tid >> 5;   // row group: rows ty*8 + r, r<8 (ty in 0..15)
  int i0 = blockIdx.x * 128;
  float acc[8][4] = {};

  for (int kc = 0; kc < nchunks; ++kc) {
    const float* A = (kc < 4) ? A1 : A2;
    int ksrc = (kc & 3) * 32;
    int kglob = kc * 32;
    #pragma unroll
    for (int q = 0; q < 2; ++q) {     // stage A (transposed into LDS)
      int f = q * 512 + tid;
      int i = f >> 3;
      int kq = (f & 7) << 2;
      int ig = i0 + i; if (ig >= M) ig = M - 1;
      float4 v = *(const float4*)(A + (size_t)ig * HID + ksrc + kq);
      As[kq + 0][i] = v.x; As[kq + 1][i] = v.y;
      As[kq + 2][i] = v.z; As[kq + 3][i] = v.w;
    }
    #pragma unroll
    for (int q = 0; q < 2; ++q) {     // stage B
      int f = q * 512 + tid;
      int k = f >> 5; int c4 = (f & 31) << 2;
      *(float4*)&Bs[k][c4] = *(const float4*)(BT + (size_t)(kglob + k) * HID + c4);
    }
    __syncthreads();
    #pragma unroll
    for (int k = 0; k < 32; ++k) {
      float a[8], b[4];
      const float4* ap = (const float4*)&As[k][ty * 8];
      float4 a0 = ap[0], a1 = ap[1];
      a[0]=a0.x; a[1]=a0.y; a[2]=a0.z; a[3]=a0.w;
      a[4]=a1.x; a[5]=a1.y; a[6]=a1.z; a[7]=a1.w;
      #pragma unroll
      for (int u = 0; u < 4; ++u) b[u] = Bs[k][tx + 32 * u];
      #pragma unroll
      for (int r = 0; r < 8; ++r)
        #pragma unroll
        for (int u = 0; u < 4; ++u)
          acc[r][u] = fmaf(a[r], b[u], acc[r][u]);
    }
    __syncthreads();
  }

  float bias_r[4], wt_r[4];
  #pragma unroll
  for (int u = 0; u < 4; ++u) { bias_r[u] = bias[tx + 32 * u]; wt_r[u] = 0.f; }
  if constexpr (TAU) {
    #pragma unroll
    for (int u = 0; u < 4; ++u) wt_r[u] = Wt[tx + 32 * u];
  }
  #pragma unroll
  for (int r = 0; r < 8; ++r) {
    int row = i0 + ty * 8 + r;
    bool ok = row < M;
    float p = 0.f;
    #pragma unroll
    for (int u = 0; u < 4; ++u) {
      float v = fmaxf(acc[r][u] + bias_r[u], 0.f);
      if (ok) C[(size_t)row * HID + tx + 32 * u] = v;
      p = fmaf(v, wt_r[u], p);
    }
    if constexpr (TAU) {
      p += __shfl_down(p, 16, 32);
      p += __shfl_down(p, 8, 32);
      p += __shfl_down(p, 4, 32);
      p += __shfl_down(p, 2, 32);
      p += __shfl_down(p, 1, 32);
      if (tx == 0) taured[ty * 8 + r] = p;
    }
  }
  if constexpr (TAU) {
    __syncthreads();
    if (tid < 128) {
      int row = i0 + tid;
      if (row < M) {
        float pre = taured[tid] + bt[0];
        float tau = (pre > 20.f) ? pre : log1pf(expf(pre));
        tau_out[row] = tau;
        // np semantics: floor(1/tau).astype(int32) overflows to INT_MIN for
        // 1/tau >= 2^31 -> n_updates <= 0 -> NOT masked even though tau<0.005.
        if (tau < 0.005f && (1.0f / tau) < 2147483648.0f) {
          int pos = atomicAdd(mcount, 1);
          mlist[pos] = row;
        }
      }
    }
  }
}

// ---------------- masked GRU, 32 nodes / block (512 threads) ----------------
__global__ __launch_bounds__(512)
void gru_kernel(const float* __restrict__ diff, float* __restrict__ h,
                const int* __restrict__ list, const int* __restrict__ count,
                const float* __restrict__ WihT, const float* __restrict__ WhhT,
                const float* __restrict__ b_ih, const float* __restrict__ b_hh) {
  int cnt = *count;
  int base = blockIdx.x * 32;
  if (base >= cnt) return;
  __shared__ float dl[32][HID];
  __shared__ float hl[32][HID];
  __shared__ int ids[32];
  int tid = threadIdx.x;
  if (tid < 32) ids[tid] = (base + tid < cnt) ? list[base + tid] : -1;
  __syncthreads();
  #pragma unroll
  for (int q = 0; q < 8; ++q) {
    int f = q * 512 + tid;
    int r = f >> 7, c = f & 127;
    int id = ids[r];
    int src = (id >= 0) ? id : 0;
    dl[r][c] = diff[(size_t)src * HID + c];
    hl[r][c] = h[(size_t)src * HID + c];
  }
  __syncthreads();
  int tx = tid & 127, ty = tid >> 7;   // ty in 0..3 -> rows ty*8..ty*8+7
  float air[8] = {}, aiz[8] = {}, ain[8] = {}, ahr[8] = {}, ahz[8] = {}, ahn[8] = {};
  for (int k = 0; k < HID; ++k) {
    float wir = WihT[k * 384 + tx];
    float wiz = WihT[k * 384 + 128 + tx];
    float win = WihT[k * 384 + 256 + tx];
    float whr = WhhT[k * 384 + tx];
    float whz = WhhT[k * 384 + 128 + tx];
    float whn = WhhT[k * 384 + 256 + tx];
    #pragma unroll
    for (int r = 0; r < 8; ++r) {
      float dk = dl[ty * 8 + r][k];
      float hk = hl[ty * 8 + r][k];
      air[r] = fmaf(dk, wir, air[r]);
      aiz[r] = fmaf(dk, wiz, aiz[r]);
      ain[r] = fmaf(dk, win, ain[r]);
      ahr[r] = fmaf(hk, whr, ahr[r]);
      ahz[r] = fmaf(hk, whz, ahz[r]);
      ahn[r] = fmaf(hk, whn, ahn[r]);
    }
  }
  float bir = b_ih[tx], biz = b_ih[128 + tx], bin = b_ih[256 + tx];
  float bhr = b_hh[tx], bhz = b_hh[128 + tx], bhn = b_hh[256 + tx];
  #pragma unroll
  for (int r = 0; r < 8; ++r) {
    int id = ids[ty * 8 + r];
    if (id < 0) continue;
    float rg = 1.f / (1.f + expf(-((air[r] + bir) + (ahr[r] + bhr))));
    float z  = 1.f / (1.f + expf(-((aiz[r] + biz) + (ahz[r] + bhz))));
    float n  = tanhf((ain[r] + bin) + rg * (ahn[r] + bhn));
    float hv = hl[ty * 8 + r][tx];
    h[(size_t)id * HID + tx] = (1.f - z) * n + z * hv;
  }
}

// ---------------- output head: out = h @ Wo^T + bo  (32 lanes / node) --------
// float4 loads (full 512B row per 32-lane group), width-32 shuffle reduce.
// Only affects `out` (not tau/mask) -> reorder noise ~1e-5, safe.
__global__ void out_kernel(const float* __restrict__ h, const float* __restrict__ Wo,
                           const float* __restrict__ bo, float* __restrict__ out, int N) {
  int g = blockIdx.x * blockDim.x + threadIdx.x;
  int node = g >> 5;
  int sub = threadIdx.x & 31;
  if (node >= N) return;
  float4 hv = *(const float4*)(h + (size_t)node * HID + sub * 4);
  float4 w0 = *(const float4*)(Wo + sub * 4);
  float4 w1 = *(const float4*)(Wo + 128 + sub * 4);
  float s0 = hv.x * w0.x + hv.y * w0.y + hv.z * w0.z + hv.w * w0.w;
  float s1 = hv.x * w1.x + hv.y * w1.y + hv.z * w1.z + hv.w * w1.w;
  for (int d = 16; d; d >>= 1) {
    s0 += __shfl_down(s0, d, 32);
    s1 += __shfl_down(s1, d, 32);
  }
  if (sub == 0) {
    out[(size_t)node * 2 + 0] = s0 + bo[0];
    out[(size_t)node * 2 + 1] = s1 + bo[1];
  }
}

extern "C" void kernel_launch(void* const* d_in, const int* in_sizes, int n_in,
                              void* d_out, int out_size, void* d_ws, size_t ws_size,
                              hipStream_t stream) {
  const float* x    = (const float*)d_in[0];
  const int*   ei   = (const int*)d_in[1];
  const float* W_in = (const float*)d_in[2];
  const float* b_in = (const float*)d_in[3];
  const float* Wd   = (const float*)d_in[4];
  const float* bd   = (const float*)d_in[5];
  const float* Wt   = (const float*)d_in[6];
  const float* bt   = (const float*)d_in[7];
  const float* W_ih = (const float*)d_in[8];
  const float* W_hh = (const float*)d_in[9];
  const float* b_ih = (const float*)d_in[10];
  const float* b_hh = (const float*)d_in[11];
  const float* Wo   = (const float*)d_in[12];
  const float* bo   = (const float*)d_in[13];

  const int N = in_sizes[0] / HID;      // 100000
  const int E = in_sizes[1] / 2;        // 1600000
  const int* rowp = ei;
  const int* colp = ei + E;
  const int nbuck = (N + (1 << BSHIFT) - 1) >> BSHIFT;   // 782 (<=1024)

  // workspace carve-up (256B aligned)
  char* p = (char*)d_ws;
  auto alloc = [&](size_t bytes) { void* r = (void*)p; p += (bytes + 255) & ~(size_t)255; return r; };
  float* hA     = (float*)alloc((size_t)N * HID * 4);
  float* hB     = (float*)alloc((size_t)N * HID * 4);
  float* diff   = (float*)alloc((size_t)N * HID * 4);
  float* WinT   = (float*)alloc(128 * 128 * 4);
  float* WdT0   = (float*)alloc(256 * 128 * 4);
  float* WdT1   = (float*)alloc(256 * 128 * 4);
  float* WihT   = (float*)alloc(128 * 384 * 4);
  float* WhhT   = (float*)alloc(128 * 384 * 4);
  float* tau0   = (float*)alloc((size_t)N * 4);
  int*   list   = (int*)alloc((size_t)N * 4);
  int*   count  = (int*)alloc(256);
  int*   countsT= (int*)alloc((size_t)1024 * NSB * 4);
  int*   btotal = (int*)alloc(1024 * 4);
  int*   bstart = (int*)alloc(1028 * 4);
  int*   offs   = (int*)alloc(((size_t)N + 1) * 4);
  int*   csrcol = (int*)alloc((size_t)E * 4);
  int2*  ebuf   = (int2*)alloc((size_t)E * 8);

  float* out_ptr = (float*)d_out;            // [N,2] flat
  float* tau_out = (float*)d_out + (size_t)N * 2;  // [N]

  // zero both layers' mask counters (ws is poisoned before every launch)
  hipMemsetAsync(count, 0, 8, stream);

  // CSR build, no global atomics, DETERMINISTIC csrcol (reused by both layers)
  // ecount also performs the weight transposes (prelude).
  ecount_kernel<<<NSB, 256, 0, stream>>>(rowp, countsT, E, nbuck,
                                         W_in, Wd, W_ih, W_hh,
                                         WinT, WdT0, WdT1, WihT, WhhT);
  bprefix_kernel<<<nbuck, NSB, 0, stream>>>(countsT, btotal, nbuck);
  bstart_kernel<<<1, 1024, 0, stream>>>(btotal, bstart, offs, N, nbuck);
  escatter_kernel<<<NSB, 256, 0, stream>>>(rowp, colp, countsT, bstart, ebuf, E, nbuck);
  bsort_kernel<<<nbuck, 256, 0, stream>>>(ebuf, bstart, offs, csrcol, N, nbuck);

  const int gemm_blocks = (N + 127) / 128;
  const int agg_blocks = (N + 3) / 4;
  const int gru_blocks = (N + 31) / 32;

  // input layer: hA = relu(x @ Win^T + b_in)
  gemm_kernel<false><<<gemm_blocks, 512, 0, stream>>>(
      x, nullptr, WinT, b_in, hA, N, 4, nullptr, nullptr, nullptr, nullptr, nullptr);

  // ---- layer 0 ----
  aggregate_kernel<<<agg_blocks, 256, 0, stream>>>(hA, offs, csrcol, diff, N);
  gemm_kernel<true><<<gemm_blocks, 512, 0, stream>>>(
      hA, diff, WdT0, bd, hB, N, 8, Wt, bt, tau0, list, count);
  gru_kernel<<<gru_blocks, 512, 0, stream>>>(diff, hB, list, count, WihT, WhhT, b_ih, b_hh);

  // ---- layer 1 ----
  aggregate_kernel<<<agg_blocks, 256, 0, stream>>>(hB, offs, csrcol, diff, N);
  gemm_kernel<true><<<gemm_blocks, 512, 0, stream>>>(
      hB, diff, WdT1, bd + 128, hA, N, 8, Wt, bt, tau_out, list, count + 1);
  gru_kernel<<<gru_blocks, 512, 0, stream>>>(diff, hA, list, count + 1, WihT, WhhT, b_ih, b_hh);

  // output head
  out_kernel<<<((size_t)N * 32 + 255) / 256, 256, 0, stream>>>(hA, Wo, bo, out_ptr, N);
}

// Round 12
// 730.496 us; speedup vs baseline: 1.0693x; 1.0461x over previous
//
#include <hip/hip_runtime.h>
#include <cstdint>
#include <cstddef>

#define HID 128
#define BSHIFT 7            // 128 nodes per bucket -> nbuck = 782 for N=100000
#define NSB 256             // scatter blocks (pass1/pass2 chunking)
#define MAXB 4096           // LDS sort capacity (avg bucket = 2046 edges)

// ======== deterministic two-pass bucket scatter (NO global atomics) ========
// ecount also absorbs the 5 weight transposes (grid-stride prelude).
__global__ __launch_bounds__(256)
void ecount_kernel(const int* __restrict__ row, int* __restrict__ countsT,
                   int E, int nbuck,
                   const float* __restrict__ W_in, const float* __restrict__ Wd,
                   const float* __restrict__ W_ih, const float* __restrict__ W_hh,
                   float* __restrict__ WinT, float* __restrict__ WdT0,
                   float* __restrict__ WdT1, float* __restrict__ WihT,
                   float* __restrict__ WhhT) {
  // --- transpose prelude (180224 elements over 65536 threads) ---
  for (int i = blockIdx.x * 256 + threadIdx.x; i < 180224; i += NSB * 256) {
    int j = i;
    if (j < 16384) { int r = j >> 7, c = j & 127; WinT[c * 128 + r] = W_in[j]; continue; }
    j -= 16384;
    if (j < 32768) { int r = j >> 8, c = j & 255; WdT0[c * 128 + r] = Wd[j]; continue; }
    j -= 32768;
    if (j < 32768) { int r = j >> 8, c = j & 255; WdT1[c * 128 + r] = Wd[32768 + j]; continue; }
    j -= 32768;
    if (j < 49152) { int r = j >> 7, c = j & 127; WihT[c * 384 + r] = W_ih[j]; continue; }
    j -= 49152;
    { int r = j >> 7, c = j & 127; WhhT[c * 384 + r] = W_hh[j]; }
  }
  // --- bucket histogram ---
  __shared__ int lh[1024];
  int b = blockIdx.x;
  for (int i = threadIdx.x; i < nbuck; i += 256) lh[i] = 0;
  __syncthreads();
  int per = (E + NSB - 1) / NSB;
  int s = b * per, e = min(s + per, E);
  for (int i = s + (int)threadIdx.x; i < e; i += 256)
    atomicAdd(&lh[row[i] >> BSHIFT], 1);   // LDS atomic, shallow
  __syncthreads();
  for (int i = threadIdx.x; i < nbuck; i += 256) countsT[i * NSB + b] = lh[i];
}

__global__ __launch_bounds__(NSB)
void bprefix_kernel(int* __restrict__ countsT, int* __restrict__ btotal, int nbuck) {
  __shared__ int sd[NSB];
  int bk = blockIdx.x;
  int t = threadIdx.x;
  int v = countsT[bk * NSB + t];
  sd[t] = v;
  __syncthreads();
  for (int off = 1; off < NSB; off <<= 1) {
    int u = (t >= off) ? sd[t - off] : 0;
    __syncthreads();
    sd[t] += u;
    __syncthreads();
  }
  countsT[bk * NSB + t] = sd[t] - v;       // exclusive within bucket
  if (t == NSB - 1) btotal[bk] = sd[t];
}

__global__ __launch_bounds__(1024)
void bstart_kernel(const int* __restrict__ btotal, int* __restrict__ bstart,
                   int* __restrict__ offsets, int N, int nbuck) {
  __shared__ int sd[1024];
  int t = threadIdx.x;
  int v = (t < nbuck) ? btotal[t] : 0;
  sd[t] = v;
  __syncthreads();
  for (int off = 1; off < 1024; off <<= 1) {
    int u = (t >= off) ? sd[t - off] : 0;
    __syncthreads();
    sd[t] += u;
    __syncthreads();
  }
  if (t < nbuck) bstart[t] = sd[t] - v;
  if (t == nbuck - 1) { bstart[nbuck] = sd[t]; offsets[N] = sd[t]; }
}

__global__ __launch_bounds__(256)
void escatter_kernel(const int* __restrict__ row, const int* __restrict__ col,
                     const int* __restrict__ countsT, const int* __restrict__ bstart,
                     int2* __restrict__ ebuf, int E, int nbuck) {
  __shared__ int lcur[1024];
  int b = blockIdx.x;
  for (int i = threadIdx.x; i < nbuck; i += 256)
    lcur[i] = bstart[i] + countsT[i * NSB + b];
  __syncthreads();
  int per = (E + NSB - 1) / NSB;
  int s = b * per, e = min(s + per, E);
  for (int i = s + (int)threadIdx.x; i < e; i += 256) {
    int r = row[i], c = col[i];
    int pos = atomicAdd(&lcur[r >> BSHIFT], 1);
    ebuf[pos] = make_int2(r, c);
  }
}

// pass 3: per-bucket LDS counting sort by row -> CSR (offsets + csrcol).
// DETERMINISM: each node's window is insertion-sorted by col; ties are
// identical values -> diff/tau/mask bit-stable across launches (round-9 fix).
__global__ __launch_bounds__(256)
void bsort_kernel(const int2* __restrict__ ebuf, const int* __restrict__ bstart,
                  int* __restrict__ offsets, int* __restrict__ csr_col,
                  int N, int nbuck) {
  __shared__ int cnt[128], off[128], cur[128];
  __shared__ int lcol[MAXB];
  int bk = blockIdx.x;
  int tid = threadIdx.x;
  int s = bstart[bk], e = bstart[bk + 1];
  int m = e - s;
  if (tid < 128) cnt[tid] = 0;
  __syncthreads();
  for (int i = s + tid; i < e; i += 256)
    atomicAdd(&cnt[ebuf[i].x & 127], 1);
  __syncthreads();
  if (tid < 128) off[tid] = cnt[tid];
  __syncthreads();
  for (int d = 1; d < 128; d <<= 1) {
    int v = 0;
    if (tid < 128 && tid >= d) v = off[tid - d];
    __syncthreads();
    if (tid < 128) off[tid] += v;
    __syncthreads();
  }
  if (tid < 128) {
    cur[tid] = off[tid] - cnt[tid];          // local exclusive
    int node = (bk << BSHIFT) + tid;
    if (node < N) offsets[node] = s + off[tid] - cnt[tid];
  }
  __syncthreads();
  if (m <= MAXB) {
    for (int i = s + tid; i < e; i += 256) {
      int2 rc = ebuf[i];
      int pos = atomicAdd(&cur[rc.x & 127], 1);   // local pos
      lcol[pos] = rc.y;
    }
    __syncthreads();
    if (tid < 128) {                               // per-node sort by col
      int b0 = off[tid] - cnt[tid], b1 = off[tid];
      for (int i = b0 + 1; i < b1; ++i) {
        int key = lcol[i];
        int j = i - 1;
        while (j >= b0 && lcol[j] > key) { lcol[j + 1] = lcol[j]; --j; }
        lcol[j + 1] = key;
      }
    }
    __syncthreads();
    for (int i = tid; i < m; i += 256) csr_col[s + i] = lcol[i];
  } else {
    // fallback (never expected for this data): unsorted direct scatter
    for (int i = s + tid; i < e; i += 256) {
      int2 rc = ebuf[i];
      int pos = atomicAdd(&cur[rc.x & 127], 1);
      csr_col[s + pos] = rc.y;
    }
  }
}

// ---------------- edge aggregation: diff[i][d] = sum_e |h[i][d]-h[col][d]| ----
// ROOFLINE (rounds 8-11): FETCH = 8 XCD x 51 MB = compulsory per-XCD L2 fill
// for random gathers; ~3.4 TB/s L2-fill serving rate; 16-deep batching neutral
// => backend-bound ceiling at ~117us. Frozen.
__global__ __launch_bounds__(256)
void aggregate_kernel(const float* __restrict__ h, const int* __restrict__ offsets,
                      const int* __restrict__ csr_col, float* __restrict__ diff,
                      int N) {
  int wave = threadIdx.x >> 6;
  int lane = threadIdx.x & 63;
  int node = blockIdx.x * 4 + wave;
  if (node >= N) return;
  int start = offsets[node], end = offsets[node + 1];
  int deg = end - start;
  const float2* hrow = (const float2*)(h + (size_t)node * HID);
  float2 hv = hrow[lane];
  float a0 = 0.f, a1 = 0.f;

  int batch = min(deg, 64);
  int myc = (lane < batch) ? csr_col[start + lane] : 0;
  int j = 0;
  for (; j + 16 <= batch; j += 16) {
    const float2* p0 = (const float2*)(h + (size_t)__shfl(myc, j + 0) * HID);
    const float2* p1 = (const float2*)(h + (size_t)__shfl(myc, j + 1) * HID);
    const float2* p2 = (const float2*)(h + (size_t)__shfl(myc, j + 2) * HID);
    const float2* p3 = (const float2*)(h + (size_t)__shfl(myc, j + 3) * HID);
    const float2* p4 = (const float2*)(h + (size_t)__shfl(myc, j + 4) * HID);
    const float2* p5 = (const float2*)(h + (size_t)__shfl(myc, j + 5) * HID);
    const float2* p6 = (const float2*)(h + (size_t)__shfl(myc, j + 6) * HID);
    const float2* p7 = (const float2*)(h + (size_t)__shfl(myc, j + 7) * HID);
    const float2* q0 = (const float2*)(h + (size_t)__shfl(myc, j + 8) * HID);
    const float2* q1 = (const float2*)(h + (size_t)__shfl(myc, j + 9) * HID);
    const float2* q2 = (const float2*)(h + (size_t)__shfl(myc, j + 10) * HID);
    const float2* q3 = (const float2*)(h + (size_t)__shfl(myc, j + 11) * HID);
    const float2* q4 = (const float2*)(h + (size_t)__shfl(myc, j + 12) * HID);
    const float2* q5 = (const float2*)(h + (size_t)__shfl(myc, j + 13) * HID);
    const float2* q6 = (const float2*)(h + (size_t)__shfl(myc, j + 14) * HID);
    const float2* q7 = (const float2*)(h + (size_t)__shfl(myc, j + 15) * HID);
    float2 x0 = p0[lane], x1 = p1[lane], x2 = p2[lane], x3 = p3[lane];
    float2 x4 = p4[lane], x5 = p5[lane], x6 = p6[lane], x7 = p7[lane];
    float2 y0 = q0[lane], y1 = q1[lane], y2 = q2[lane], y3 = q3[lane];
    float2 y4 = q4[lane], y5 = q5[lane], y6 = q6[lane], y7 = q7[lane];
    a0 += fabsf(hv.x - x0.x) + fabsf(hv.x - x1.x) + fabsf(hv.x - x2.x) + fabsf(hv.x - x3.x)
        + fabsf(hv.x - x4.x) + fabsf(hv.x - x5.x) + fabsf(hv.x - x6.x) + fabsf(hv.x - x7.x);
    a1 += fabsf(hv.y - x0.y) + fabsf(hv.y - x1.y) + fabsf(hv.y - x2.y) + fabsf(hv.y - x3.y)
        + fabsf(hv.y - x4.y) + fabsf(hv.y - x5.y) + fabsf(hv.y - x6.y) + fabsf(hv.y - x7.y);
    a0 += fabsf(hv.x - y0.x) + fabsf(hv.x - y1.x) + fabsf(hv.x - y2.x) + fabsf(hv.x - y3.x)
        + fabsf(hv.x - y4.x) + fabsf(hv.x - y5.x) + fabsf(hv.x - y6.x) + fabsf(hv.x - y7.x);
    a1 += fabsf(hv.y - y0.y) + fabsf(hv.y - y1.y) + fabsf(hv.y - y2.y) + fabsf(hv.y - y3.y)
        + fabsf(hv.y - y4.y) + fabsf(hv.y - y5.y) + fabsf(hv.y - y6.y) + fabsf(hv.y - y7.y);
  }
  for (; j + 8 <= batch; j += 8) {
    const float2* p0 = (const float2*)(h + (size_t)__shfl(myc, j + 0) * HID);
    const float2* p1 = (const float2*)(h + (size_t)__shfl(myc, j + 1) * HID);
    const float2* p2 = (const float2*)(h + (size_t)__shfl(myc, j + 2) * HID);
    const float2* p3 = (const float2*)(h + (size_t)__shfl(myc, j + 3) * HID);
    const float2* p4 = (const float2*)(h + (size_t)__shfl(myc, j + 4) * HID);
    const float2* p5 = (const float2*)(h + (size_t)__shfl(myc, j + 5) * HID);
    const float2* p6 = (const float2*)(h + (size_t)__shfl(myc, j + 6) * HID);
    const float2* p7 = (const float2*)(h + (size_t)__shfl(myc, j + 7) * HID);
    float2 x0 = p0[lane], x1 = p1[lane], x2 = p2[lane], x3 = p3[lane];
    float2 x4 = p4[lane], x5 = p5[lane], x6 = p6[lane], x7 = p7[lane];
    a0 += fabsf(hv.x - x0.x) + fabsf(hv.x - x1.x) + fabsf(hv.x - x2.x) + fabsf(hv.x - x3.x)
        + fabsf(hv.x - x4.x) + fabsf(hv.x - x5.x) + fabsf(hv.x - x6.x) + fabsf(hv.x - x7.x);
    a1 += fabsf(hv.y - x0.y) + fabsf(hv.y - x1.y) + fabsf(hv.y - x2.y) + fabsf(hv.y - x3.y)
        + fabsf(hv.y - x4.y) + fabsf(hv.y - x5.y) + fabsf(hv.y - x6.y) + fabsf(hv.y - x7.y);
  }
  for (; j < batch; ++j) {
    const float2* p = (const float2*)(h + (size_t)__shfl(myc, j) * HID);
    float2 x = p[lane];
    a0 += fabsf(hv.x - x.x);
    a1 += fabsf(hv.y - x.y);
  }
  for (int e = start + 64; e < end; ++e) {
    const float2* p = (const float2*)(h + (size_t)csr_col[e] * HID);
    float2 x = p[lane];
    a0 += fabsf(hv.x - x.x);
    a1 += fabsf(hv.y - x.y);
  }
  *(float2*)(diff + (size_t)node * HID + 2 * lane) = make_float2(a0, a1);
}

// ---------------- tiled fp32 GEMM: C = relu([A1|A2] @ BT + bias), opt tau ----
// Round-12: 64-row x 128-col tile, 256 threads, thread owns 8 rows x 4
// CONTIGUOUS cols (4tx..4tx+3). Rationale vs round-11 (117us @ 512thr/128-tile):
// (1) 1563 blocks vs 782 -> load-imbalance tail 31% -> 16% (782 = 3.05/CU);
// (2) B-read = one ds_read_b128 (was 4x ds_read_b32), C-store = dwordx4
//     (was 4x dword), A-reads become wave-broadcast;
// (3) LDS 25.6KB -> 6 blocks/CU resident.
// Per-element C accumulation order (k-sequential fmaf) unchanged -> h
// bit-identical; only tau partial-sum grouping changes (ulp-noise class).
template<bool TAU>
__global__ __launch_bounds__(256)
void gemm_kernel(const float* __restrict__ A1, const float* __restrict__ A2,
                 const float* __restrict__ BT, const float* __restrict__ bias,
                 float* __restrict__ C, int M, int nchunks,
                 const float* __restrict__ Wt, const float* __restrict__ bt,
                 float* __restrict__ tau_out, int* __restrict__ mlist,
                 int* __restrict__ mcount) {
  __shared__ float As[32][68];    // [k][i], i<64, pad keeps 16B align per k-row
  __shared__ float Bs[32][128];   // [k][c]
  __shared__ float taured[64];
  int tid = threadIdx.x;
  int tx = tid & 31;   // col group: cols 4tx .. 4tx+3
  int ty = tid >> 5;   // row group: rows ty*8 + r, r<8 (ty in 0..7)
  int i0 = blockIdx.x * 64;
  float acc[8][4] = {};

  for (int kc = 0; kc < nchunks; ++kc) {
    const float* A = (kc < 4) ? A1 : A2;
    int ksrc = (kc & 3) * 32;
    int kglob = kc * 32;
    #pragma unroll
    for (int q = 0; q < 2; ++q) {     // stage A (transposed into LDS): 512 f4
      int f = q * 256 + tid;
      int i = f >> 3;
      int kq = (f & 7) << 2;
      int ig = i0 + i; if (ig >= M) ig = M - 1;
      float4 v = *(const float4*)(A + (size_t)ig * HID + ksrc + kq);
      As[kq + 0][i] = v.x; As[kq + 1][i] = v.y;
      As[kq + 2][i] = v.z; As[kq + 3][i] = v.w;
    }
    #pragma unroll
    for (int q = 0; q < 4; ++q) {     // stage B: 1024 f4
      int f = q * 256 + tid;
      int k = f >> 5; int c4 = (f & 31) << 2;
      *(float4*)&Bs[k][c4] = *(const float4*)(BT + (size_t)(kglob + k) * HID + c4);
    }
    __syncthreads();
    #pragma unroll
    for (int k = 0; k < 32; ++k) {
      float a[8];
      const float4* ap = (const float4*)&As[k][ty * 8];   // wave-broadcast
      float4 a0 = ap[0], a1 = ap[1];
      a[0]=a0.x; a[1]=a0.y; a[2]=a0.z; a[3]=a0.w;
      a[4]=a1.x; a[5]=a1.y; a[6]=a1.z; a[7]=a1.w;
      float4 b4 = *(const float4*)&Bs[k][tx * 4];         // one b128
      #pragma unroll
      for (int r = 0; r < 8; ++r) {
        acc[r][0] = fmaf(a[r], b4.x, acc[r][0]);
        acc[r][1] = fmaf(a[r], b4.y, acc[r][1]);
        acc[r][2] = fmaf(a[r], b4.z, acc[r][2]);
        acc[r][3] = fmaf(a[r], b4.w, acc[r][3]);
      }
    }
    __syncthreads();
  }

  float4 bias4 = *(const float4*)(bias + tx * 4);
  float bias_r[4] = {bias4.x, bias4.y, bias4.z, bias4.w};
  float wt_r[4] = {0.f, 0.f, 0.f, 0.f};
  if constexpr (TAU) {
    float4 w4 = *(const float4*)(Wt + tx * 4);
    wt_r[0] = w4.x; wt_r[1] = w4.y; wt_r[2] = w4.z; wt_r[3] = w4.w;
  }
  #pragma unroll
  for (int r = 0; r < 8; ++r) {
    int row = i0 + ty * 8 + r;
    bool ok = row < M;
    float v0 = fmaxf(acc[r][0] + bias_r[0], 0.f);
    float v1 = fmaxf(acc[r][1] + bias_r[1], 0.f);
    float v2 = fmaxf(acc[r][2] + bias_r[2], 0.f);
    float v3 = fmaxf(acc[r][3] + bias_r[3], 0.f);
    if (ok) {
      float4 v4 = make_float4(v0, v1, v2, v3);
      *(float4*)(C + (size_t)row * HID + tx * 4) = v4;    // dwordx4 store
    }
    if constexpr (TAU) {
      float p = v0 * wt_r[0];
      p = fmaf(v1, wt_r[1], p);
      p = fmaf(v2, wt_r[2], p);
      p = fmaf(v3, wt_r[3], p);
      p += __shfl_down(p, 16, 32);
      p += __shfl_down(p, 8, 32);
      p += __shfl_down(p, 4, 32);
      p += __shfl_down(p, 2, 32);
      p += __shfl_down(p, 1, 32);
      if (tx == 0) taured[ty * 8 + r] = p;
    }
  }
  if constexpr (TAU) {
    __syncthreads();
    if (tid < 64) {
      int row = i0 + tid;
      if (row < M) {
        float pre = taured[tid] + bt[0];
        float tau = (pre > 20.f) ? pre : log1pf(expf(pre));
        tau_out[row] = tau;
        // np semantics: floor(1/tau).astype(int32) overflows to INT_MIN for
        // 1/tau >= 2^31 -> n_updates <= 0 -> NOT masked even though tau<0.005.
        if (tau < 0.005f && (1.0f / tau) < 2147483648.0f) {
          int pos = atomicAdd(mcount, 1);
          mlist[pos] = row;
        }
      }
    }
  }
}

// ---------------- masked GRU, 32 nodes / block (512 threads) ----------------
__global__ __launch_bounds__(512)
void gru_kernel(const float* __restrict__ diff, float* __restrict__ h,
                const int* __restrict__ list, const int* __restrict__ count,
                const float* __restrict__ WihT, const float* __restrict__ WhhT,
                const float* __restrict__ b_ih, const float* __restrict__ b_hh) {
  int cnt = *count;
  int base = blockIdx.x * 32;
  if (base >= cnt) return;
  __shared__ float dl[32][HID];
  __shared__ float hl[32][HID];
  __shared__ int ids[32];
  int tid = threadIdx.x;
  if (tid < 32) ids[tid] = (base + tid < cnt) ? list[base + tid] : -1;
  __syncthreads();
  #pragma unroll
  for (int q = 0; q < 8; ++q) {
    int f = q * 512 + tid;
    int r = f >> 7, c = f & 127;
    int id = ids[r];
    int src = (id >= 0) ? id : 0;
    dl[r][c] = diff[(size_t)src * HID + c];
    hl[r][c] = h[(size_t)src * HID + c];
  }
  __syncthreads();
  int tx = tid & 127, ty = tid >> 7;   // ty in 0..3 -> rows ty*8..ty*8+7
  float air[8] = {}, aiz[8] = {}, ain[8] = {}, ahr[8] = {}, ahz[8] = {}, ahn[8] = {};
  for (int k = 0; k < HID; ++k) {
    float wir = WihT[k * 384 + tx];
    float wiz = WihT[k * 384 + 128 + tx];
    float win = WihT[k * 384 + 256 + tx];
    float whr = WhhT[k * 384 + tx];
    float whz = WhhT[k * 384 + 128 + tx];
    float whn = WhhT[k * 384 + 256 + tx];
    #pragma unroll
    for (int r = 0; r < 8; ++r) {
      float dk = dl[ty * 8 + r][k];
      float hk = hl[ty * 8 + r][k];
      air[r] = fmaf(dk, wir, air[r]);
      aiz[r] = fmaf(dk, wiz, aiz[r]);
      ain[r] = fmaf(dk, win, ain[r]);
      ahr[r] = fmaf(hk, whr, ahr[r]);
      ahz[r] = fmaf(hk, whz, ahz[r]);
      ahn[r] = fmaf(hk, whn, ahn[r]);
    }
  }
  float bir = b_ih[tx], biz = b_ih[128 + tx], bin = b_ih[256 + tx];
  float bhr = b_hh[tx], bhz = b_hh[128 + tx], bhn = b_hh[256 + tx];
  #pragma unroll
  for (int r = 0; r < 8; ++r) {
    int id = ids[ty * 8 + r];
    if (id < 0) continue;
    float rg = 1.f / (1.f + expf(-((air[r] + bir) + (ahr[r] + bhr))));
    float z  = 1.f / (1.f + expf(-((aiz[r] + biz) + (ahz[r] + bhz))));
    float n  = tanhf((ain[r] + bin) + rg * (ahn[r] + bhn));
    float hv = hl[ty * 8 + r][tx];
    h[(size_t)id * HID + tx] = (1.f - z) * n + z * hv;
  }
}

// ---------------- output head: out = h @ Wo^T + bo  (32 lanes / node) --------
__global__ void out_kernel(const float* __restrict__ h, const float* __restrict__ Wo,
                           const float* __restrict__ bo, float* __restrict__ out, int N) {
  int g = blockIdx.x * blockDim.x + threadIdx.x;
  int node = g >> 5;
  int sub = threadIdx.x & 31;
  if (node >= N) return;
  float4 hv = *(const float4*)(h + (size_t)node * HID + sub * 4);
  float4 w0 = *(const float4*)(Wo + sub * 4);
  float4 w1 = *(const float4*)(Wo + 128 + sub * 4);
  float s0 = hv.x * w0.x + hv.y * w0.y + hv.z * w0.z + hv.w * w0.w;
  float s1 = hv.x * w1.x + hv.y * w1.y + hv.z * w1.z + hv.w * w1.w;
  for (int d = 16; d; d >>= 1) {
    s0 += __shfl_down(s0, d, 32);
    s1 += __shfl_down(s1, d, 32);
  }
  if (sub == 0) {
    out[(size_t)node * 2 + 0] = s0 + bo[0];
    out[(size_t)node * 2 + 1] = s1 + bo[1];
  }
}

extern "C" void kernel_launch(void* const* d_in, const int* in_sizes, int n_in,
                              void* d_out, int out_size, void* d_ws, size_t ws_size,
                              hipStream_t stream) {
  const float* x    = (const float*)d_in[0];
  const int*   ei   = (const int*)d_in[1];
  const float* W_in = (const float*)d_in[2];
  const float* b_in = (const float*)d_in[3];
  const float* Wd   = (const float*)d_in[4];
  const float* bd   = (const float*)d_in[5];
  const float* Wt   = (const float*)d_in[6];
  const float* bt   = (const float*)d_in[7];
  const float* W_ih = (const float*)d_in[8];
  const float* W_hh = (const float*)d_in[9];
  const float* b_ih = (const float*)d_in[10];
  const float* b_hh = (const float*)d_in[11];
  const float* Wo   = (const float*)d_in[12];
  const float* bo   = (const float*)d_in[13];

  const int N = in_sizes[0] / HID;      // 100000
  const int E = in_sizes[1] / 2;        // 1600000
  const int* rowp = ei;
  const int* colp = ei + E;
  const int nbuck = (N + (1 << BSHIFT) - 1) >> BSHIFT;   // 782 (<=1024)

  // workspace carve-up (256B aligned)
  char* p = (char*)d_ws;
  auto alloc = [&](size_t bytes) { void* r = (void*)p; p += (bytes + 255) & ~(size_t)255; return r; };
  float* hA     = (float*)alloc((size_t)N * HID * 4);
  float* hB     = (float*)alloc((size_t)N * HID * 4);
  float* diff   = (float*)alloc((size_t)N * HID * 4);
  float* WinT   = (float*)alloc(128 * 128 * 4);
  float* WdT0   = (float*)alloc(256 * 128 * 4);
  float* WdT1   = (float*)alloc(256 * 128 * 4);
  float* WihT   = (float*)alloc(128 * 384 * 4);
  float* WhhT   = (float*)alloc(128 * 384 * 4);
  float* tau0   = (float*)alloc((size_t)N * 4);
  int*   list   = (int*)alloc((size_t)N * 4);
  int*   count  = (int*)alloc(256);
  int*   countsT= (int*)alloc((size_t)1024 * NSB * 4);
  int*   btotal = (int*)alloc(1024 * 4);
  int*   bstart = (int*)alloc(1028 * 4);
  int*   offs   = (int*)alloc(((size_t)N + 1) * 4);
  int*   csrcol = (int*)alloc((size_t)E * 4);
  int2*  ebuf   = (int2*)alloc((size_t)E * 8);

  float* out_ptr = (float*)d_out;            // [N,2] flat
  float* tau_out = (float*)d_out + (size_t)N * 2;  // [N]

  // zero both layers' mask counters (ws is poisoned before every launch)
  hipMemsetAsync(count, 0, 8, stream);

  // CSR build, no global atomics, DETERMINISTIC csrcol (reused by both layers)
  // ecount also performs the weight transposes (prelude).
  ecount_kernel<<<NSB, 256, 0, stream>>>(rowp, countsT, E, nbuck,
                                         W_in, Wd, W_ih, W_hh,
                                         WinT, WdT0, WdT1, WihT, WhhT);
  bprefix_kernel<<<nbuck, NSB, 0, stream>>>(countsT, btotal, nbuck);
  bstart_kernel<<<1, 1024, 0, stream>>>(btotal, bstart, offs, N, nbuck);
  escatter_kernel<<<NSB, 256, 0, stream>>>(rowp, colp, countsT, bstart, ebuf, E, nbuck);
  bsort_kernel<<<nbuck, 256, 0, stream>>>(ebuf, bstart, offs, csrcol, N, nbuck);

  const int gemm_blocks = (N + 63) / 64;
  const int agg_blocks = (N + 3) / 4;
  const int gru_blocks = (N + 31) / 32;

  // input layer: hA = relu(x @ Win^T + b_in)
  gemm_kernel<false><<<gemm_blocks, 256, 0, stream>>>(
      x, nullptr, WinT, b_in, hA, N, 4, nullptr, nullptr, nullptr, nullptr, nullptr);

  // ---- layer 0 ----
  aggregate_kernel<<<agg_blocks, 256, 0, stream>>>(hA, offs, csrcol, diff, N);
  gemm_kernel<true><<<gemm_blocks, 256, 0, stream>>>(
      hA, diff, WdT0, bd, hB, N, 8, Wt, bt, tau0, list, count);
  gru_kernel<<<gru_blocks, 512, 0, stream>>>(diff, hB, list, count, WihT, WhhT, b_ih, b_hh);

  // ---- layer 1 ----
  aggregate_kernel<<<agg_blocks, 256, 0, stream>>>(hB, offs, csrcol, diff, N);
  gemm_kernel<true><<<gemm_blocks, 256, 0, stream>>>(
      hB, diff, WdT1, bd + 128, hA, N, 8, Wt, bt, tau_out, list, count + 1);
  gru_kernel<<<gru_blocks, 512, 0, stream>>>(diff, hA, list, count + 1, WihT, WhhT, b_ih, b_hh);

  // output head
  out_kernel<<<((size_t)N * 32 + 255) / 256, 256, 0, stream>>>(hA, Wo, bo, out_ptr, N);
}